// Round 11
// baseline (583.586 us; speedup 1.0000x reference)
//
#include <hip/hip_runtime.h>
#include <hip/hip_fp16.h>
#include <stdint.h>

#define TROWS 51712   // 512*101
#define NCITY 101
#define BATCH 512
#define EDIM  128
#define NBH   4096    // BATCH*8 heads

using half_t = _Float16;
typedef __attribute__((ext_vector_type(8))) _Float16 h8;
typedef __attribute__((ext_vector_type(4))) _Float16 h4;
typedef __attribute__((ext_vector_type(4))) float   f32x4;

typedef __attribute__((address_space(1))) const unsigned int gu32;
typedef __attribute__((address_space(3))) unsigned int lu32;
static __device__ __forceinline__ void async16(const void* g, const void* l) {
    __builtin_amdgcn_global_load_lds((gu32*)g, (lu32*)(uint32_t)(uintptr_t)l, 16, 0, 0);
}

// ---------------- weight prep: transpose to [n][k] fp16 ----------------
__global__ __launch_bounds__(256)
void transpose_w(const float* __restrict__ src, half_t* __restrict__ dst,
                 int K, int N, int dstOff, int dstLS)
{
    int gid = blockIdx.x * 256 + threadIdx.x;
    int total = 3 * K * N;
    if (gid >= total) return;
    int l = gid / (K * N);
    int r = gid - l * (K * N);
    int k = r / N;
    int n = r - k * N;
    dst[(size_t)l * dstLS + dstOff + (size_t)n * K + k] = (half_t)src[gid];
}

__global__ __launch_bounds__(256)
void pack_bias(const float* __restrict__ bq, const float* __restrict__ bk,
               const float* __restrict__ bv, float* __restrict__ dst)
{
    int gid = blockIdx.x * 256 + threadIdx.x;
    if (gid >= 3 * 384) return;
    int l = gid / 384, c = gid - l * 384;
    float v = (c < 128) ? bq[l * 128 + c]
            : (c < 256) ? bk[l * 128 + c - 128]
                        : bv[l * 128 + c - 256];
    dst[gid] = v;
}

// ---------------- embedding (fp16 activation mirror only) ----------------
__global__ __launch_bounds__(256)
void embed_kernel(const float* __restrict__ s, const int* __restrict__ d,
                  const float* __restrict__ e_w, const float* __restrict__ e_b,
                  const float* __restrict__ ep_w, const float* __restrict__ ep_b,
                  half_t* __restrict__ xh)
{
    int gid = blockIdx.x * 256 + threadIdx.x;      // over TROWS*128
    int row = gid >> 7;
    int c   = gid & 127;
    int b = row / NCITY;
    int n = row - b * NCITY;
    const float* sp = s + ((size_t)b * NCITY + n) * 2;
    float v;
    if (n == 0) {
        v = sp[0] * ep_w[c] + sp[1] * ep_w[128 + c] + ep_b[c];
    } else {
        float dv = (float)d[b * NCITY + n];
        v = sp[0] * e_w[c] + sp[1] * e_w[128 + c] + dv * e_w[256 + c] + e_b[c];
    }
    xh[gid] = (half_t)v;
}

// ---------------- fp16 GEMM, 1-barrier double-buffered pipeline ----------------
// MODE 0: QKV — scatter fp16 to Q/K/V, all [bh][tok][16]
// MODE 1: out fp16 y = acc + bias + res(fp16), fused BN stats (O-proj)
template<int MODE, int KSTEPS>
__global__ __launch_bounds__(256)
void gemm_tile(const half_t* __restrict__ A, const half_t* __restrict__ B,
               const float* __restrict__ bias, const half_t* __restrict__ res,
               void* __restrict__ out, void* __restrict__ outK, void* __restrict__ outV,
               float* __restrict__ stats, int Nout)
{
    constexpr int K = KSTEPS * 32;
    __shared__ alignas(16) half_t sA[2][128 * 32];
    __shared__ alignas(16) half_t sB[2][128 * 32];

    const int tid  = threadIdx.x;
    const int wave = tid >> 6, lane = tid & 63;
    const int n0 = blockIdx.x * 128;
    const int m0 = blockIdx.y * 128;

    const int sr = wave * 16 + (lane >> 2);
    const int sc = (lane & 3) * 8;
    const half_t* gA = A + (size_t)(m0 + sr) * K + sc;
    const half_t* gB = B + (size_t)(n0 + sr) * K + sc;
    const int ldst = wave * 512;

    const int quad = lane >> 4, l16 = lane & 15;
    const int wm = (wave >> 1) * 64, wn = (wave & 1) * 64;

    f32x4 acc[4][4] = {};

    async16(gA,                  &sA[0][ldst]);
    async16(gA + (size_t)64 * K, &sA[0][2048 + ldst]);
    async16(gB,                  &sB[0][ldst]);
    async16(gB + (size_t)64 * K, &sB[0][2048 + ldst]);

    for (int ks = 0; ks < KSTEPS; ++ks) {
        __syncthreads();
        if (ks + 1 < KSTEPS) {
            const int k0 = (ks + 1) * 32;
            const int nb = (ks + 1) & 1;
            async16(gA + k0,                  &sA[nb][ldst]);
            async16(gA + (size_t)64 * K + k0, &sA[nb][2048 + ldst]);
            async16(gB + k0,                  &sB[nb][ldst]);
            async16(gB + (size_t)64 * K + k0, &sB[nb][2048 + ldst]);
        }
        const int cb = ks & 1;
        h8 af[4], bf[4];
        #pragma unroll
        for (int mi = 0; mi < 4; ++mi)
            af[mi] = *(const h8*)(&sA[cb][(wm + mi * 16 + l16) * 32 + quad * 8]);
        #pragma unroll
        for (int ni = 0; ni < 4; ++ni)
            bf[ni] = *(const h8*)(&sB[cb][(wn + ni * 16 + l16) * 32 + quad * 8]);
        #pragma unroll
        for (int mi = 0; mi < 4; ++mi)
        #pragma unroll
        for (int ni = 0; ni < 4; ++ni)
            acc[mi][ni] = __builtin_amdgcn_mfma_f32_16x16x32_f16(af[mi], bf[ni], acc[mi][ni], 0, 0, 0);
    }

    #pragma unroll
    for (int ni = 0; ni < 4; ++ni) {
        int col = n0 + wn + ni * 16 + l16;
        float bvv = bias[col];
        float s = 0.0f, ss = 0.0f;
        #pragma unroll
        for (int mi = 0; mi < 4; ++mi) {
            #pragma unroll
            for (int r = 0; r < 4; ++r) {
                int row = m0 + wm + mi * 16 + quad * 4 + r;
                float v = acc[mi][ni][r] + bvv;
                if (MODE == 0) {
                    int b   = row / NCITY;
                    int tok = row - b * NCITY;
                    int which = col >> 7;
                    int h     = (col >> 4) & 7;
                    int bh    = b * 8 + h;
                    half_t hv = (half_t)v;
                    half_t* dst = (which == 0) ? (half_t*)out
                                : (which == 1) ? (half_t*)outK : (half_t*)outV;
                    dst[((size_t)bh * NCITY + tok) * 16 + l16] = hv;
                } else {
                    size_t off = (size_t)row * Nout + col;
                    float o = v + (float)res[off];
                    ((half_t*)out)[off] = (half_t)o;
                    s += o; ss += o * o;
                }
            }
        }
        if (MODE == 1) {
            s  += __shfl_xor(s, 16);  s  += __shfl_xor(s, 32);
            ss += __shfl_xor(ss, 16); ss += __shfl_xor(ss, 32);
            if (quad == 0) {
                atomicAdd(&stats[col], s);
                atomicAdd(&stats[128 + col], ss);
            }
        }
    }
}

// ---------------- fused FF1(ReLU)+FF2: h1 never leaves LDS ----------------
// LDS = sX + sH only (64 KB -> 2 blocks/CU). Weights read as direct global
// fragments (L2-resident: all 404 blocks read the same 256 KB).
__global__ __launch_bounds__(256)
void ff_fused(const half_t* __restrict__ xh, const half_t* __restrict__ w1,
              const half_t* __restrict__ w2, const float* __restrict__ bf1,
              const float* __restrict__ bf2, const half_t* __restrict__ res,
              half_t* __restrict__ y16, float* __restrict__ stats)
{
    __shared__ alignas(16) half_t sX[4][128 * 32];   // xh: [kc][row][32]
    __shared__ alignas(16) half_t sH[4][128 * 32];   // h1 chunk: [kc][row][32]

    const int tid  = threadIdx.x;
    const int wave = tid >> 6, lane = tid & 63;
    const int m0 = blockIdx.x * 128;

    const int sr = wave * 16 + (lane >> 2);   // 0..63
    const int sc = (lane & 3) * 8;
    const int ldst = wave * 512;

    const int quad = lane >> 4, l16 = lane & 15;
    const int wm = (wave >> 1) * 64, wn = (wave & 1) * 64;

    // stage xh tile (K=128): 4 k-chunks x 2 row-halves
    #pragma unroll
    for (int kc = 0; kc < 4; ++kc) {
        async16(xh + (size_t)(m0 + sr) * 128 + kc * 32 + sc,      &sX[kc][ldst]);
        async16(xh + (size_t)(m0 + 64 + sr) * 128 + kc * 32 + sc, &sX[kc][2048 + ldst]);
    }

    f32x4 acc2[4][4] = {};

    for (int j = 0; j < 4; ++j) {
        __syncthreads();   // j=0: drains sX staging; j>0: prev FF2 done with sH

        // FF1: h1[m][c] for c-chunk j; B-frags direct from global (L2-hot)
        f32x4 acc1[4][4] = {};
        #pragma unroll
        for (int kc = 0; kc < 4; ++kc) {
            h8 af[4], bf[4];
            #pragma unroll
            for (int mi = 0; mi < 4; ++mi)
                af[mi] = *(const h8*)(&sX[kc][(wm + mi * 16 + l16) * 32 + quad * 8]);
            #pragma unroll
            for (int ni = 0; ni < 4; ++ni)
                bf[ni] = *(const h8*)(w1 + (size_t)(j * 128 + wn + ni * 16 + l16) * 128
                                          + kc * 32 + quad * 8);
            #pragma unroll
            for (int mi = 0; mi < 4; ++mi)
            #pragma unroll
            for (int ni = 0; ni < 4; ++ni)
                acc1[mi][ni] = __builtin_amdgcn_mfma_f32_16x16x32_f16(af[mi], bf[ni], acc1[mi][ni], 0, 0, 0);
        }
        // ReLU + bias -> sH in A-frag layout [kc][row][32]
        #pragma unroll
        for (int ni = 0; ni < 4; ++ni) {
            int c = wn + ni * 16 + l16;          // chunk-local 0..127
            float bvv = bf1[j * 128 + c];
            #pragma unroll
            for (int mi = 0; mi < 4; ++mi)
            #pragma unroll
            for (int r = 0; r < 4; ++r) {
                int row = wm + mi * 16 + quad * 4 + r;
                float v = acc1[mi][ni][r] + bvv;
                v = v > 0.0f ? v : 0.0f;
                sH[c >> 5][row * 32 + (c & 31)] = (half_t)v;
            }
        }
        __syncthreads();   // sH visible

        // FF2 partial: acc2 += h1chunk * wf2chunk^T; B-frags direct global
        #pragma unroll
        for (int kc = 0; kc < 4; ++kc) {
            h8 af[4], bf[4];
            #pragma unroll
            for (int mi = 0; mi < 4; ++mi)
                af[mi] = *(const h8*)(&sH[kc][(wm + mi * 16 + l16) * 32 + quad * 8]);
            #pragma unroll
            for (int ni = 0; ni < 4; ++ni)
                bf[ni] = *(const h8*)(w2 + (size_t)(wn + ni * 16 + l16) * 512
                                          + j * 128 + kc * 32 + quad * 8);
            #pragma unroll
            for (int mi = 0; mi < 4; ++mi)
            #pragma unroll
            for (int ni = 0; ni < 4; ++ni)
                acc2[mi][ni] = __builtin_amdgcn_mfma_f32_16x16x32_f16(af[mi], bf[ni], acc2[mi][ni], 0, 0, 0);
        }
    }

    // epilogue (MODE 1 semantics)
    #pragma unroll
    for (int ni = 0; ni < 4; ++ni) {
        int col = wn + ni * 16 + l16;
        float bvv = bf2[col];
        float s = 0.0f, ss = 0.0f;
        #pragma unroll
        for (int mi = 0; mi < 4; ++mi) {
            #pragma unroll
            for (int r = 0; r < 4; ++r) {
                int row = m0 + wm + mi * 16 + quad * 4 + r;
                size_t off = (size_t)row * 128 + col;
                float o = acc2[mi][ni][r] + bvv + (float)res[off];
                y16[off] = (half_t)o;
                s += o; ss += o * o;
            }
        }
        s  += __shfl_xor(s, 16);  s  += __shfl_xor(s, 32);
        ss += __shfl_xor(ss, 16); ss += __shfl_xor(ss, 32);
        if (quad == 0) {
            atomicAdd(&stats[col], s);
            atomicAdd(&stats[128 + col], ss);
        }
    }
}

// ---------------- LDS-free fp16 MFMA attention: one wave per (bh, q-tile) ----------------
__global__ __launch_bounds__(256)
void attn_kernel(const half_t* __restrict__ Qh, const half_t* __restrict__ Kh,
                 const half_t* __restrict__ V, half_t* __restrict__ oh)
{
    const int wid = blockIdx.x * 4 + (threadIdx.x >> 6);
    const int bh = wid / 7;
    const int it = wid - bh * 7;
    if (bh >= NBH) return;
    const int b = bh >> 3, h = bh & 7;

    const int lane = threadIdx.x & 63, quad = lane >> 4, l16 = lane & 15;
    const int s0 = (((quad & 1) * 2)    ) * 16 + l16;
    const int s1 = (((quad & 1) * 2) + 1) * 16 + l16;
    const bool hi2 = (quad >> 1) != 0;

    const half_t* qbase = Qh + (size_t)bh * NCITY * 16;
    const half_t* kbase = Kh + (size_t)bh * NCITY * 16;
    const half_t* vbase = V  + (size_t)bh * NCITY * 16;

    h8 qf = {};
    if (quad < 2)
        qf = *reinterpret_cast<const h8*>(qbase + (it * 16 + l16) * 16 + quad * 8);

    f32x4 S[7];
    #pragma unroll
    for (int jt = 0; jt < 7; ++jt) {
        h8 kf = {};
        if (quad < 2)
            kf = *reinterpret_cast<const h8*>(kbase + (jt * 16 + l16) * 16 + quad * 8);
        f32x4 a = {};
        a = __builtin_amdgcn_mfma_f32_16x16x32_f16(kf, qf, a, 0, 0, 0);
        S[jt] = a;
    }
    float m = -1e30f;
    #pragma unroll
    for (int jt = 0; jt < 7; ++jt)
        #pragma unroll
        for (int r = 0; r < 4; ++r) {
            int jg = jt * 16 + quad * 4 + r;
            float sv = (jg < NCITY) ? S[jt][r] * 0.25f : -1e30f;
            S[jt][r] = sv;
            m = fmaxf(m, sv);
        }
    m = fmaxf(m, __shfl_xor(m, 16));
    m = fmaxf(m, __shfl_xor(m, 32));
    float sum = 0.0f;
    #pragma unroll
    for (int jt = 0; jt < 7; ++jt)
        #pragma unroll
        for (int r = 0; r < 4; ++r) {
            float e = __expf(S[jt][r] - m);
            S[jt][r] = e;
            sum += e;
        }
    sum += __shfl_xor(sum, 16);
    sum += __shfl_xor(sum, 32);
    float inv = 1.0f / sum;
    #pragma unroll
    for (int jt = 0; jt < 7; ++jt)
        #pragma unroll
        for (int r = 0; r < 4; ++r) S[jt][r] *= inv;

    f32x4 O = {};
    #pragma unroll
    for (int p = 0; p < 4; ++p) {
        h8 vf;
        #pragma unroll
        for (int jj = 0; jj < 8; ++jj)
            vf[jj] = vbase[(size_t)(p * 32 + quad * 8 + jj) * 16 + l16];
        float pj[8];
        #pragma unroll
        for (int r = 0; r < 4; ++r) {
            float a0 = __shfl(S[2 * p][r],     s0);
            float b0 = __shfl(S[2 * p + 1][r], s0);
            float a1 = __shfl(S[2 * p][r],     s1);
            float b1 = __shfl(S[2 * p + 1][r], s1);
            pj[r]     = hi2 ? b0 : a0;
            pj[4 + r] = hi2 ? b1 : a1;
        }
        h8 ph;
        #pragma unroll
        for (int jj = 0; jj < 8; ++jj)
            ph[jj] = (half_t)pj[jj];
        O = __builtin_amdgcn_mfma_f32_16x16x32_f16(ph, vf, O, 0, 0, 0);
    }
    #pragma unroll
    for (int r = 0; r < 4; ++r) {
        int q = it * 16 + quad * 4 + r;
        if (q < NCITY)
            oh[((size_t)b * NCITY + q) * 128 + h * 16 + l16] = (half_t)O[r];
    }
}

// ---------------- BatchNorm finalize (+ zero stats for next user) ----------------
__global__ void bn_final(float* __restrict__ stats, const float* __restrict__ g,
                         const float* __restrict__ be, float* __restrict__ sh)
{
    int c = threadIdx.x;  // 128 threads
    const float invN = 1.0f / (float)TROWS;
    float mean = stats[c] * invN;
    float var  = stats[128 + c] * invN - mean * mean;
    float inv  = rsqrtf(var + 1e-5f);
    float scl  = g[c] * inv;
    sh[c]       = scl;
    sh[128 + c] = be[c] - mean * scl;
    stats[c] = 0.0f;
    stats[128 + c] = 0.0f;
}

__global__ __launch_bounds__(256)
void bn_apply(const h8* __restrict__ y, const float* __restrict__ sh,
              half_t* __restrict__ xh, float* __restrict__ dst32)
{
    int gid = blockIdx.x * 256 + threadIdx.x;   // over TROWS*16 (8 ch each)
    int c = (gid & 15) * 8;
    h8 v = y[gid];
    h8 hv;
    float o[8];
    #pragma unroll
    for (int r = 0; r < 8; ++r) {
        o[r] = (float)v[r] * sh[c + r] + sh[128 + c + r];
        hv[r] = (half_t)o[r];
    }
    *reinterpret_cast<h8*>(xh + (size_t)gid * 8) = hv;
    if (dst32) {
        f32x4 lo = { o[0], o[1], o[2], o[3] };
        f32x4 hi = { o[4], o[5], o[6], o[7] };
        ((f32x4*)dst32)[gid * 2]     = lo;
        ((f32x4*)dst32)[gid * 2 + 1] = hi;
    }
}

// ---------------- launch ----------------
extern "C" void kernel_launch(void* const* d_in, const int* in_sizes, int n_in,
                              void* d_out, int out_size, void* d_ws, size_t ws_size,
                              hipStream_t stream)
{
    const float* s    = (const float*)d_in[0];
    const int*   dd   = (const int*)d_in[1];
    const float* e_w  = (const float*)d_in[2];
    const float* e_b  = (const float*)d_in[3];
    const float* ep_w = (const float*)d_in[4];
    const float* ep_b = (const float*)d_in[5];
    const float* Wq   = (const float*)d_in[6];
    const float* bq   = (const float*)d_in[7];
    const float* Wk   = (const float*)d_in[8];
    const float* bk   = (const float*)d_in[9];
    const float* Wv   = (const float*)d_in[10];
    const float* bv   = (const float*)d_in[11];
    const float* Wo   = (const float*)d_in[12];
    const float* bo   = (const float*)d_in[13];
    const float* Wf1  = (const float*)d_in[14];
    const float* bf1  = (const float*)d_in[15];
    const float* Wf2  = (const float*)d_in[16];
    const float* bf2  = (const float*)d_in[17];
    const float* g1   = (const float*)d_in[18];
    const float* be1  = (const float*)d_in[19];
    const float* g2   = (const float*)d_in[20];
    const float* be2  = (const float*)d_in[21];

    char* ws = (char*)d_ws;
    size_t off = 0;
    auto alloc = [&](size_t bytes) -> void* {
        void* p = ws + off;
        off += (bytes + 255) & ~(size_t)255;
        return p;
    };
    half_t* y16   = (half_t*)alloc((size_t)TROWS * 128 * 2);
    half_t* xh    = (half_t*)alloc((size_t)TROWS * 128 * 2);
    half_t* Qh    = (half_t*)alloc((size_t)NBH * NCITY * 16 * 2);
    half_t* Kh    = (half_t*)alloc((size_t)NBH * NCITY * 16 * 2);
    half_t* Vb    = (half_t*)alloc((size_t)NBH * NCITY * 16 * 2);
    half_t* oh    = (half_t*)alloc((size_t)TROWS * 128 * 2);
    half_t* wqkv  = (half_t*)alloc((size_t)3 * 384 * 128 * 2);
    half_t* wo    = (half_t*)alloc((size_t)3 * 128 * 128 * 2);
    half_t* wf1   = (half_t*)alloc((size_t)3 * 512 * 128 * 2);
    half_t* wf2   = (half_t*)alloc((size_t)3 * 128 * 512 * 2);
    float*  bqkv  = (float*) alloc((size_t)3 * 384 * 4);
    float*  stats = (float*) alloc(256 * 4);
    float*  sh    = (float*) alloc(256 * 4);

    dim3 blk(256);

    // stats must start zeroed (ws is poisoned); bn_final re-zeroes after each use
    hipMemsetAsync(stats, 0, 256 * 4, stream);

    // weight prep
    transpose_w<<<dim3(192), blk, 0, stream>>>(Wq,  wqkv, 128, 128, 0,     49152);
    transpose_w<<<dim3(192), blk, 0, stream>>>(Wk,  wqkv, 128, 128, 16384, 49152);
    transpose_w<<<dim3(192), blk, 0, stream>>>(Wv,  wqkv, 128, 128, 32768, 49152);
    transpose_w<<<dim3(192), blk, 0, stream>>>(Wo,  wo,   128, 128, 0,     16384);
    transpose_w<<<dim3(768), blk, 0, stream>>>(Wf1, wf1,  128, 512, 0,     65536);
    transpose_w<<<dim3(768), blk, 0, stream>>>(Wf2, wf2,  512, 128, 0,     65536);
    pack_bias<<<dim3(5), blk, 0, stream>>>(bq, bk, bv, bqkv);

    embed_kernel<<<dim3(TROWS * 128 / 256), blk, 0, stream>>>(s, dd, e_w, e_b, ep_w, ep_b, xh);

    for (int l = 0; l < 3; ++l) {
        // QKV -> Q/K/V all [bh][tok][16]
        gemm_tile<0, 4><<<dim3(3, 404), blk, 0, stream>>>(xh, wqkv + (size_t)l * 49152,
                                                          bqkv + l * 384, nullptr,
                                                          Qh, Kh, Vb, nullptr, 384);
        // attention (LDS-free fp16 MFMA)
        attn_kernel<<<dim3(7168), blk, 0, stream>>>(Qh, Kh, Vb, oh);
        // O-proj + bias + residual(xh) + fused BN1 stats -> y16
        gemm_tile<1, 4><<<dim3(1, 404), blk, 0, stream>>>(oh, wo + (size_t)l * 16384,
                                                          bo + l * 128, xh,
                                                          y16, nullptr, nullptr, stats, 128);
        bn_final<<<dim3(1), dim3(128), 0, stream>>>(stats, g1 + l * 128, be1 + l * 128, sh);
        bn_apply<<<dim3(TROWS * 16 / 256), blk, 0, stream>>>((const h8*)y16, sh, xh, nullptr);
        // fused FF1+FF2 (+ residual + BN2 stats) -> y16
        ff_fused<<<dim3(404), blk, 0, stream>>>(xh, wf1 + (size_t)l * 65536,
                                                wf2 + (size_t)l * 65536,
                                                bf1 + l * 512, bf2 + l * 128, xh,
                                                y16, stats);
        bn_final<<<dim3(1), dim3(128), 0, stream>>>(stats, g2 + l * 128, be2 + l * 128, sh);
        bn_apply<<<dim3(TROWS * 16 / 256), blk, 0, stream>>>((const h8*)y16, sh, xh,
                                                             (l == 2) ? (float*)d_out : nullptr);
    }
}

// Round 12
// 546.148 us; speedup vs baseline: 1.0685x; 1.0685x over previous
//
#include <hip/hip_runtime.h>
#include <hip/hip_fp16.h>
#include <stdint.h>

#define TROWS 51712   // 512*101
#define NCITY 101
#define BATCH 512
#define EDIM  128
#define NBH   4096    // BATCH*8 heads

using half_t = _Float16;
typedef __attribute__((ext_vector_type(8))) _Float16 h8;
typedef __attribute__((ext_vector_type(4))) _Float16 h4;
typedef __attribute__((ext_vector_type(4))) float   f32x4;

typedef __attribute__((address_space(1))) const unsigned int gu32;
typedef __attribute__((address_space(3))) unsigned int lu32;
static __device__ __forceinline__ void async16(const void* g, const void* l) {
    __builtin_amdgcn_global_load_lds((gu32*)g, (lu32*)(uint32_t)(uintptr_t)l, 16, 0, 0);
}

// ---------------- one-shot weight prep: all transposes + bias pack ----------------
__global__ __launch_bounds__(256)
void prep_kernel(const float* __restrict__ Wq, const float* __restrict__ Wk,
                 const float* __restrict__ Wv, const float* __restrict__ Wo,
                 const float* __restrict__ Wf1, const float* __restrict__ Wf2,
                 const float* __restrict__ bq, const float* __restrict__ bk,
                 const float* __restrict__ bv,
                 half_t* __restrict__ wqkv, half_t* __restrict__ wo,
                 half_t* __restrict__ wf1, half_t* __restrict__ wf2,
                 float* __restrict__ bqkv)
{
    const int which = blockIdx.y;
    const int gid = blockIdx.x * 256 + threadIdx.x;
    if (which <= 2) {            // Wq/Wk/Wv -> wqkv [l][384][128], block off which*128 rows
        if (gid >= 3 * 128 * 128) return;
        const float* src = (which == 0) ? Wq : (which == 1) ? Wk : Wv;
        int l = gid >> 14, r = gid & 16383, k = r >> 7, n = r & 127;
        wqkv[(size_t)l * 49152 + which * 16384 + n * 128 + k] = (half_t)src[gid];
    } else if (which == 3) {     // Wo -> [l][128][128]
        if (gid >= 3 * 128 * 128) return;
        int l = gid >> 14, r = gid & 16383, k = r >> 7, n = r & 127;
        wo[(size_t)l * 16384 + n * 128 + k] = (half_t)Wo[gid];
    } else if (which == 4) {     // Wf1 [l][128][512] -> [l][512][128]
        if (gid >= 3 * 128 * 512) return;
        int l = gid >> 16, r = gid & 65535, k = r >> 9, n = r & 511;
        wf1[(size_t)l * 65536 + n * 128 + k] = (half_t)Wf1[gid];
    } else if (which == 5) {     // Wf2 [l][512][128] -> [l][128][512]
        if (gid >= 3 * 512 * 128) return;
        int l = gid >> 16, r = gid & 65535, k = r >> 7, n = r & 127;
        wf2[(size_t)l * 65536 + n * 512 + k] = (half_t)Wf2[gid];
    } else {                     // bias pack
        if (gid >= 3 * 384) return;
        int l = gid / 384, c = gid - l * 384;
        float v = (c < 128) ? bq[l * 128 + c]
                : (c < 256) ? bk[l * 128 + c - 128]
                            : bv[l * 128 + c - 256];
        bqkv[gid] = v;
    }
}

// ---------------- embedding (fp16 activation mirror only) ----------------
__global__ __launch_bounds__(256)
void embed_kernel(const float* __restrict__ s, const int* __restrict__ d,
                  const float* __restrict__ e_w, const float* __restrict__ e_b,
                  const float* __restrict__ ep_w, const float* __restrict__ ep_b,
                  half_t* __restrict__ xh)
{
    int gid = blockIdx.x * 256 + threadIdx.x;      // over TROWS*128
    int row = gid >> 7;
    int c   = gid & 127;
    int b = row / NCITY;
    int n = row - b * NCITY;
    const float* sp = s + ((size_t)b * NCITY + n) * 2;
    float v;
    if (n == 0) {
        v = sp[0] * ep_w[c] + sp[1] * ep_w[128 + c] + ep_b[c];
    } else {
        float dv = (float)d[b * NCITY + n];
        v = sp[0] * e_w[c] + sp[1] * e_w[128 + c] + dv * e_w[256 + c] + e_b[c];
    }
    xh[gid] = (half_t)v;
}

// ---------------- fp16 GEMM, 1-barrier double-buffered pipeline ----------------
// MODE 0: QKV — scatter fp16 to Q/K/V, all [bh][tok][16]
// MODE 1: out fp16 y = acc + bias + res(fp16), fused BN stats (O-proj)
template<int MODE, int KSTEPS>
__global__ __launch_bounds__(256)
void gemm_tile(const half_t* __restrict__ A, const half_t* __restrict__ B,
               const float* __restrict__ bias, const half_t* __restrict__ res,
               void* __restrict__ out, void* __restrict__ outK, void* __restrict__ outV,
               float* __restrict__ stats, int Nout)
{
    constexpr int K = KSTEPS * 32;
    __shared__ alignas(16) half_t sA[2][128 * 32];
    __shared__ alignas(16) half_t sB[2][128 * 32];

    const int tid  = threadIdx.x;
    const int wave = tid >> 6, lane = tid & 63;
    const int n0 = blockIdx.x * 128;
    const int m0 = blockIdx.y * 128;

    const int sr = wave * 16 + (lane >> 2);
    const int sc = (lane & 3) * 8;
    const half_t* gA = A + (size_t)(m0 + sr) * K + sc;
    const half_t* gB = B + (size_t)(n0 + sr) * K + sc;
    const int ldst = wave * 512;

    const int quad = lane >> 4, l16 = lane & 15;
    const int wm = (wave >> 1) * 64, wn = (wave & 1) * 64;

    f32x4 acc[4][4] = {};

    async16(gA,                  &sA[0][ldst]);
    async16(gA + (size_t)64 * K, &sA[0][2048 + ldst]);
    async16(gB,                  &sB[0][ldst]);
    async16(gB + (size_t)64 * K, &sB[0][2048 + ldst]);

    for (int ks = 0; ks < KSTEPS; ++ks) {
        __syncthreads();
        if (ks + 1 < KSTEPS) {
            const int k0 = (ks + 1) * 32;
            const int nb = (ks + 1) & 1;
            async16(gA + k0,                  &sA[nb][ldst]);
            async16(gA + (size_t)64 * K + k0, &sA[nb][2048 + ldst]);
            async16(gB + k0,                  &sB[nb][ldst]);
            async16(gB + (size_t)64 * K + k0, &sB[nb][2048 + ldst]);
        }
        const int cb = ks & 1;
        h8 af[4], bf[4];
        #pragma unroll
        for (int mi = 0; mi < 4; ++mi)
            af[mi] = *(const h8*)(&sA[cb][(wm + mi * 16 + l16) * 32 + quad * 8]);
        #pragma unroll
        for (int ni = 0; ni < 4; ++ni)
            bf[ni] = *(const h8*)(&sB[cb][(wn + ni * 16 + l16) * 32 + quad * 8]);
        #pragma unroll
        for (int mi = 0; mi < 4; ++mi)
        #pragma unroll
        for (int ni = 0; ni < 4; ++ni)
            acc[mi][ni] = __builtin_amdgcn_mfma_f32_16x16x32_f16(af[mi], bf[ni], acc[mi][ni], 0, 0, 0);
    }

    #pragma unroll
    for (int ni = 0; ni < 4; ++ni) {
        int col = n0 + wn + ni * 16 + l16;
        float bvv = bias[col];
        float s = 0.0f, ss = 0.0f;
        #pragma unroll
        for (int mi = 0; mi < 4; ++mi) {
            #pragma unroll
            for (int r = 0; r < 4; ++r) {
                int row = m0 + wm + mi * 16 + quad * 4 + r;
                float v = acc[mi][ni][r] + bvv;
                if (MODE == 0) {
                    int b   = row / NCITY;
                    int tok = row - b * NCITY;
                    int which = col >> 7;
                    int h     = (col >> 4) & 7;
                    int bh    = b * 8 + h;
                    half_t hv = (half_t)v;
                    half_t* dst = (which == 0) ? (half_t*)out
                                : (which == 1) ? (half_t*)outK : (half_t*)outV;
                    dst[((size_t)bh * NCITY + tok) * 16 + l16] = hv;
                } else {
                    size_t off = (size_t)row * Nout + col;
                    float o = v + (float)res[off];
                    ((half_t*)out)[off] = (half_t)o;
                    s += o; ss += o * o;
                }
            }
        }
        if (MODE == 1) {
            s  += __shfl_xor(s, 16);  s  += __shfl_xor(s, 32);
            ss += __shfl_xor(ss, 16); ss += __shfl_xor(ss, 32);
            if (quad == 0) {
                atomicAdd(&stats[col], s);
                atomicAdd(&stats[128 + col], ss);
            }
        }
    }
}

// ---------------- fused FF1(ReLU)+FF2 (r10 version): h1 never leaves LDS ----------------
__global__ __launch_bounds__(256)
void ff_fused(const half_t* __restrict__ xh, const half_t* __restrict__ w1,
              const half_t* __restrict__ w2, const float* __restrict__ bf1,
              const float* __restrict__ bf2, const half_t* __restrict__ res,
              half_t* __restrict__ y16, float* __restrict__ stats)
{
    __shared__ alignas(16) half_t sX[4][128 * 32];   // xh: [kc][row][32]
    __shared__ alignas(16) half_t sW1[4][128 * 32];  // wf1 chunk
    __shared__ alignas(16) half_t sW2[4][128 * 32];  // wf2 chunk
    __shared__ alignas(16) half_t sH[4][128 * 32];   // h1 chunk

    const int tid  = threadIdx.x;
    const int wave = tid >> 6, lane = tid & 63;
    const int m0 = blockIdx.x * 128;

    const int sr = wave * 16 + (lane >> 2);
    const int sc = (lane & 3) * 8;
    const int ldst = wave * 512;

    const int quad = lane >> 4, l16 = lane & 15;
    const int wm = (wave >> 1) * 64, wn = (wave & 1) * 64;

    #pragma unroll
    for (int kc = 0; kc < 4; ++kc) {
        async16(xh + (size_t)(m0 + sr) * 128 + kc * 32 + sc,      &sX[kc][ldst]);
        async16(xh + (size_t)(m0 + 64 + sr) * 128 + kc * 32 + sc, &sX[kc][2048 + ldst]);
    }

    f32x4 acc2[4][4] = {};

    for (int j = 0; j < 4; ++j) {
        __syncthreads();
        #pragma unroll
        for (int kc = 0; kc < 4; ++kc) {
            async16(w1 + (size_t)(j * 128 + sr) * 128 + kc * 32 + sc,      &sW1[kc][ldst]);
            async16(w1 + (size_t)(j * 128 + 64 + sr) * 128 + kc * 32 + sc, &sW1[kc][2048 + ldst]);
        }
        #pragma unroll
        for (int kc = 0; kc < 4; ++kc) {
            async16(w2 + (size_t)sr * 512 + j * 128 + kc * 32 + sc,        &sW2[kc][ldst]);
            async16(w2 + (size_t)(64 + sr) * 512 + j * 128 + kc * 32 + sc, &sW2[kc][2048 + ldst]);
        }
        __syncthreads();

        f32x4 acc1[4][4] = {};
        #pragma unroll
        for (int kc = 0; kc < 4; ++kc) {
            h8 af[4], bf[4];
            #pragma unroll
            for (int mi = 0; mi < 4; ++mi)
                af[mi] = *(const h8*)(&sX[kc][(wm + mi * 16 + l16) * 32 + quad * 8]);
            #pragma unroll
            for (int ni = 0; ni < 4; ++ni)
                bf[ni] = *(const h8*)(&sW1[kc][(wn + ni * 16 + l16) * 32 + quad * 8]);
            #pragma unroll
            for (int mi = 0; mi < 4; ++mi)
            #pragma unroll
            for (int ni = 0; ni < 4; ++ni)
                acc1[mi][ni] = __builtin_amdgcn_mfma_f32_16x16x32_f16(af[mi], bf[ni], acc1[mi][ni], 0, 0, 0);
        }
        #pragma unroll
        for (int ni = 0; ni < 4; ++ni) {
            int c = wn + ni * 16 + l16;
            float bvv = bf1[j * 128 + c];
            #pragma unroll
            for (int mi = 0; mi < 4; ++mi)
            #pragma unroll
            for (int r = 0; r < 4; ++r) {
                int row = wm + mi * 16 + quad * 4 + r;
                float v = acc1[mi][ni][r] + bvv;
                v = v > 0.0f ? v : 0.0f;
                sH[c >> 5][row * 32 + (c & 31)] = (half_t)v;
            }
        }
        __syncthreads();

        #pragma unroll
        for (int kc = 0; kc < 4; ++kc) {
            h8 af[4], bf[4];
            #pragma unroll
            for (int mi = 0; mi < 4; ++mi)
                af[mi] = *(const h8*)(&sH[kc][(wm + mi * 16 + l16) * 32 + quad * 8]);
            #pragma unroll
            for (int ni = 0; ni < 4; ++ni)
                bf[ni] = *(const h8*)(&sW2[kc][(wn + ni * 16 + l16) * 32 + quad * 8]);
            #pragma unroll
            for (int mi = 0; mi < 4; ++mi)
            #pragma unroll
            for (int ni = 0; ni < 4; ++ni)
                acc2[mi][ni] = __builtin_amdgcn_mfma_f32_16x16x32_f16(af[mi], bf[ni], acc2[mi][ni], 0, 0, 0);
        }
    }

    #pragma unroll
    for (int ni = 0; ni < 4; ++ni) {
        int col = wn + ni * 16 + l16;
        float bvv = bf2[col];
        float s = 0.0f, ss = 0.0f;
        #pragma unroll
        for (int mi = 0; mi < 4; ++mi) {
            #pragma unroll
            for (int r = 0; r < 4; ++r) {
                int row = m0 + wm + mi * 16 + quad * 4 + r;
                size_t off = (size_t)row * 128 + col;
                float o = acc2[mi][ni][r] + bvv + (float)res[off];
                y16[off] = (half_t)o;
                s += o; ss += o * o;
            }
        }
        s  += __shfl_xor(s, 16);  s  += __shfl_xor(s, 32);
        ss += __shfl_xor(ss, 16); ss += __shfl_xor(ss, 32);
        if (quad == 0) {
            atomicAdd(&stats[col], s);
            atomicAdd(&stats[128 + col], ss);
        }
    }
}

// ---------------- LDS-free fp16 MFMA attention: one wave per (bh, q-tile) ----------------
__global__ __launch_bounds__(256)
void attn_kernel(const half_t* __restrict__ Qh, const half_t* __restrict__ Kh,
                 const half_t* __restrict__ V, half_t* __restrict__ oh)
{
    const int wid = blockIdx.x * 4 + (threadIdx.x >> 6);
    const int bh = wid / 7;
    const int it = wid - bh * 7;
    if (bh >= NBH) return;
    const int b = bh >> 3, h = bh & 7;

    const int lane = threadIdx.x & 63, quad = lane >> 4, l16 = lane & 15;
    const int s0 = (((quad & 1) * 2)    ) * 16 + l16;
    const int s1 = (((quad & 1) * 2) + 1) * 16 + l16;
    const bool hi2 = (quad >> 1) != 0;

    const half_t* qbase = Qh + (size_t)bh * NCITY * 16;
    const half_t* kbase = Kh + (size_t)bh * NCITY * 16;
    const half_t* vbase = V  + (size_t)bh * NCITY * 16;

    h8 qf = {};
    if (quad < 2)
        qf = *reinterpret_cast<const h8*>(qbase + (it * 16 + l16) * 16 + quad * 8);

    f32x4 S[7];
    #pragma unroll
    for (int jt = 0; jt < 7; ++jt) {
        h8 kf = {};
        if (quad < 2)
            kf = *reinterpret_cast<const h8*>(kbase + (jt * 16 + l16) * 16 + quad * 8);
        f32x4 a = {};
        a = __builtin_amdgcn_mfma_f32_16x16x32_f16(kf, qf, a, 0, 0, 0);
        S[jt] = a;
    }
    float m = -1e30f;
    #pragma unroll
    for (int jt = 0; jt < 7; ++jt)
        #pragma unroll
        for (int r = 0; r < 4; ++r) {
            int jg = jt * 16 + quad * 4 + r;
            float sv = (jg < NCITY) ? S[jt][r] * 0.25f : -1e30f;
            S[jt][r] = sv;
            m = fmaxf(m, sv);
        }
    m = fmaxf(m, __shfl_xor(m, 16));
    m = fmaxf(m, __shfl_xor(m, 32));
    float sum = 0.0f;
    #pragma unroll
    for (int jt = 0; jt < 7; ++jt)
        #pragma unroll
        for (int r = 0; r < 4; ++r) {
            float e = __expf(S[jt][r] - m);
            S[jt][r] = e;
            sum += e;
        }
    sum += __shfl_xor(sum, 16);
    sum += __shfl_xor(sum, 32);
    float inv = 1.0f / sum;
    #pragma unroll
    for (int jt = 0; jt < 7; ++jt)
        #pragma unroll
        for (int r = 0; r < 4; ++r) S[jt][r] *= inv;

    f32x4 O = {};
    #pragma unroll
    for (int p = 0; p < 4; ++p) {
        h8 vf;
        #pragma unroll
        for (int jj = 0; jj < 8; ++jj)
            vf[jj] = vbase[(size_t)(p * 32 + quad * 8 + jj) * 16 + l16];
        float pj[8];
        #pragma unroll
        for (int r = 0; r < 4; ++r) {
            float a0 = __shfl(S[2 * p][r],     s0);
            float b0 = __shfl(S[2 * p + 1][r], s0);
            float a1 = __shfl(S[2 * p][r],     s1);
            float b1 = __shfl(S[2 * p + 1][r], s1);
            pj[r]     = hi2 ? b0 : a0;
            pj[4 + r] = hi2 ? b1 : a1;
        }
        h8 ph;
        #pragma unroll
        for (int jj = 0; jj < 8; ++jj)
            ph[jj] = (half_t)pj[jj];
        O = __builtin_amdgcn_mfma_f32_16x16x32_f16(ph, vf, O, 0, 0, 0);
    }
    #pragma unroll
    for (int r = 0; r < 4; ++r) {
        int q = it * 16 + quad * 4 + r;
        if (q < NCITY)
            oh[((size_t)b * NCITY + q) * 128 + h * 16 + l16] = (half_t)O[r];
    }
}

// ---------------- BatchNorm apply (bn_final folded in) ----------------
__global__ __launch_bounds__(256)
void bn_apply(const h8* __restrict__ y, const float* __restrict__ stats,
              const float* __restrict__ g, const float* __restrict__ be,
              half_t* __restrict__ xh, float* __restrict__ dst32)
{
    __shared__ float sh[256];
    const int tid = threadIdx.x;
    if (tid < 128) {
        const float invN = 1.0f / (float)TROWS;
        float mean = stats[tid] * invN;
        float var  = stats[128 + tid] * invN - mean * mean;
        float inv  = rsqrtf(var + 1e-5f);
        float scl  = g[tid] * inv;
        sh[tid]       = scl;
        sh[128 + tid] = be[tid] - mean * scl;
    }
    __syncthreads();

    int gid = blockIdx.x * 256 + tid;   // over TROWS*16 (8 ch each)
    int c = (gid & 15) * 8;
    h8 v = y[gid];
    h8 hv;
    float o[8];
    #pragma unroll
    for (int r = 0; r < 8; ++r) {
        o[r] = (float)v[r] * sh[c + r] + sh[128 + c + r];
        hv[r] = (half_t)o[r];
    }
    *reinterpret_cast<h8*>(xh + (size_t)gid * 8) = hv;
    if (dst32) {
        f32x4 lo = { o[0], o[1], o[2], o[3] };
        f32x4 hi = { o[4], o[5], o[6], o[7] };
        ((f32x4*)dst32)[gid * 2]     = lo;
        ((f32x4*)dst32)[gid * 2 + 1] = hi;
    }
}

// ---------------- launch ----------------
extern "C" void kernel_launch(void* const* d_in, const int* in_sizes, int n_in,
                              void* d_out, int out_size, void* d_ws, size_t ws_size,
                              hipStream_t stream)
{
    const float* s    = (const float*)d_in[0];
    const int*   dd   = (const int*)d_in[1];
    const float* e_w  = (const float*)d_in[2];
    const float* e_b  = (const float*)d_in[3];
    const float* ep_w = (const float*)d_in[4];
    const float* ep_b = (const float*)d_in[5];
    const float* Wq   = (const float*)d_in[6];
    const float* bq   = (const float*)d_in[7];
    const float* Wk   = (const float*)d_in[8];
    const float* bk   = (const float*)d_in[9];
    const float* Wv   = (const float*)d_in[10];
    const float* bv   = (const float*)d_in[11];
    const float* Wo   = (const float*)d_in[12];
    const float* bo   = (const float*)d_in[13];
    const float* Wf1  = (const float*)d_in[14];
    const float* bf1  = (const float*)d_in[15];
    const float* Wf2  = (const float*)d_in[16];
    const float* bf2  = (const float*)d_in[17];
    const float* g1   = (const float*)d_in[18];
    const float* be1  = (const float*)d_in[19];
    const float* g2   = (const float*)d_in[20];
    const float* be2  = (const float*)d_in[21];

    char* ws = (char*)d_ws;
    size_t off = 0;
    auto alloc = [&](size_t bytes) -> void* {
        void* p = ws + off;
        off += (bytes + 255) & ~(size_t)255;
        return p;
    };
    half_t* y16   = (half_t*)alloc((size_t)TROWS * 128 * 2);
    half_t* xh    = (half_t*)alloc((size_t)TROWS * 128 * 2);
    half_t* Qh    = (half_t*)alloc((size_t)NBH * NCITY * 16 * 2);
    half_t* Kh    = (half_t*)alloc((size_t)NBH * NCITY * 16 * 2);
    half_t* Vb    = (half_t*)alloc((size_t)NBH * NCITY * 16 * 2);
    half_t* oh    = (half_t*)alloc((size_t)TROWS * 128 * 2);
    half_t* wqkv  = (half_t*)alloc((size_t)3 * 384 * 128 * 2);
    half_t* wo    = (half_t*)alloc((size_t)3 * 128 * 128 * 2);
    half_t* wf1   = (half_t*)alloc((size_t)3 * 512 * 128 * 2);
    half_t* wf2   = (half_t*)alloc((size_t)3 * 128 * 512 * 2);
    float*  bqkv  = (float*) alloc((size_t)3 * 384 * 4);
    float*  stats = (float*) alloc(6 * 256 * 4);   // one 256-float buffer per BN instance

    dim3 blk(256);

    // zero all 6 stats buffers once (ws is poisoned)
    hipMemsetAsync(stats, 0, 6 * 256 * 4, stream);

    // one-shot weight prep
    prep_kernel<<<dim3(768, 7), blk, 0, stream>>>(Wq, Wk, Wv, Wo, Wf1, Wf2, bq, bk, bv,
                                                  wqkv, wo, wf1, wf2, bqkv);

    embed_kernel<<<dim3(TROWS * 128 / 256), blk, 0, stream>>>(s, dd, e_w, e_b, ep_w, ep_b, xh);

    for (int l = 0; l < 3; ++l) {
        float* st1 = stats + (size_t)(l * 2) * 256;
        float* st2 = stats + (size_t)(l * 2 + 1) * 256;
        // QKV -> Q/K/V all [bh][tok][16]
        gemm_tile<0, 4><<<dim3(3, 404), blk, 0, stream>>>(xh, wqkv + (size_t)l * 49152,
                                                          bqkv + l * 384, nullptr,
                                                          Qh, Kh, Vb, nullptr, 384);
        // attention (LDS-free fp16 MFMA)
        attn_kernel<<<dim3(7168), blk, 0, stream>>>(Qh, Kh, Vb, oh);
        // O-proj + bias + residual(xh) + fused BN1 stats -> y16
        gemm_tile<1, 4><<<dim3(1, 404), blk, 0, stream>>>(oh, wo + (size_t)l * 16384,
                                                          bo + l * 128, xh,
                                                          y16, nullptr, nullptr, st1, 128);
        bn_apply<<<dim3(TROWS * 16 / 256), blk, 0, stream>>>((const h8*)y16, st1,
                                                             g1 + l * 128, be1 + l * 128,
                                                             xh, nullptr);
        // fused FF1+FF2 (+ residual + BN2 stats) -> y16
        ff_fused<<<dim3(404), blk, 0, stream>>>(xh, wf1 + (size_t)l * 65536,
                                                wf2 + (size_t)l * 65536,
                                                bf1 + l * 512, bf2 + l * 128, xh,
                                                y16, st2);
        bn_apply<<<dim3(TROWS * 16 / 256), blk, 0, stream>>>((const h8*)y16, st2,
                                                             g2 + l * 128, be2 + l * 128,
                                                             xh, (l == 2) ? (float*)d_out : nullptr);
    }
}

// Round 13
// 511.780 us; speedup vs baseline: 1.1403x; 1.0672x over previous
//
#include <hip/hip_runtime.h>
#include <hip/hip_fp16.h>
#include <stdint.h>

#define TROWS 51712   // 512*101
#define NCITY 101
#define BATCH 512
#define EDIM  128
#define NBH   4096    // BATCH*8 heads

using half_t = _Float16;
typedef __attribute__((ext_vector_type(8))) _Float16 h8;
typedef __attribute__((ext_vector_type(4))) _Float16 h4;
typedef __attribute__((ext_vector_type(4))) float   f32x4;

typedef __attribute__((address_space(1))) const unsigned int gu32;
typedef __attribute__((address_space(3))) unsigned int lu32;
static __device__ __forceinline__ void async16(const void* g, const void* l) {
    __builtin_amdgcn_global_load_lds((gu32*)g, (lu32*)(uint32_t)(uintptr_t)l, 16, 0, 0);
}

// ---------------- one-shot weight prep: all transposes + bias pack ----------------
__global__ __launch_bounds__(256)
void prep_kernel(const float* __restrict__ Wq, const float* __restrict__ Wk,
                 const float* __restrict__ Wv, const float* __restrict__ Wo,
                 const float* __restrict__ Wf1, const float* __restrict__ Wf2,
                 const float* __restrict__ bq, const float* __restrict__ bk,
                 const float* __restrict__ bv,
                 half_t* __restrict__ wqkv, half_t* __restrict__ wo,
                 half_t* __restrict__ wf1, half_t* __restrict__ wf2,
                 float* __restrict__ bqkv)
{
    const int which = blockIdx.y;
    const int gid = blockIdx.x * 256 + threadIdx.x;
    if (which <= 2) {
        if (gid >= 3 * 128 * 128) return;
        const float* src = (which == 0) ? Wq : (which == 1) ? Wk : Wv;
        int l = gid >> 14, r = gid & 16383, k = r >> 7, n = r & 127;
        wqkv[(size_t)l * 49152 + which * 16384 + n * 128 + k] = (half_t)src[gid];
    } else if (which == 3) {
        if (gid >= 3 * 128 * 128) return;
        int l = gid >> 14, r = gid & 16383, k = r >> 7, n = r & 127;
        wo[(size_t)l * 16384 + n * 128 + k] = (half_t)Wo[gid];
    } else if (which == 4) {
        if (gid >= 3 * 128 * 512) return;
        int l = gid >> 16, r = gid & 65535, k = r >> 9, n = r & 511;
        wf1[(size_t)l * 65536 + n * 128 + k] = (half_t)Wf1[gid];
    } else if (which == 5) {
        if (gid >= 3 * 512 * 128) return;
        int l = gid >> 16, r = gid & 65535, k = r >> 7, n = r & 127;
        wf2[(size_t)l * 65536 + n * 512 + k] = (half_t)Wf2[gid];
    } else {
        if (gid >= 3 * 384) return;
        int l = gid / 384, c = gid - l * 384;
        float v = (c < 128) ? bq[l * 128 + c]
                : (c < 256) ? bk[l * 128 + c - 128]
                            : bv[l * 128 + c - 256];
        bqkv[gid] = v;
    }
}

// ---------------- embedding (fp16 activation mirror only) ----------------
__global__ __launch_bounds__(256)
void embed_kernel(const float* __restrict__ s, const int* __restrict__ d,
                  const float* __restrict__ e_w, const float* __restrict__ e_b,
                  const float* __restrict__ ep_w, const float* __restrict__ ep_b,
                  half_t* __restrict__ xh)
{
    int gid = blockIdx.x * 256 + threadIdx.x;      // over TROWS*128
    int row = gid >> 7;
    int c   = gid & 127;
    int b = row / NCITY;
    int n = row - b * NCITY;
    const float* sp = s + ((size_t)b * NCITY + n) * 2;
    float v;
    if (n == 0) {
        v = sp[0] * ep_w[c] + sp[1] * ep_w[128 + c] + ep_b[c];
    } else {
        float dv = (float)d[b * NCITY + n];
        v = sp[0] * e_w[c] + sp[1] * e_w[128 + c] + dv * e_w[256 + c] + e_b[c];
    }
    xh[gid] = (half_t)v;
}

// ---------------- fp16 GEMM, 1-barrier double-buffered pipeline ----------------
// MODE 0: QKV — scatter fp16 to Q/K/V, all [bh][tok][16]
// MODE 1: out fp16 y = acc + bias + res(fp16), fused BN stats (O-proj)
template<int MODE, int KSTEPS>
__global__ __launch_bounds__(256)
void gemm_tile(const half_t* __restrict__ A, const half_t* __restrict__ B,
               const float* __restrict__ bias, const half_t* __restrict__ res,
               void* __restrict__ out, void* __restrict__ outK, void* __restrict__ outV,
               float* __restrict__ stats, int Nout)
{
    constexpr int K = KSTEPS * 32;
    __shared__ alignas(16) half_t sA[2][128 * 32];
    __shared__ alignas(16) half_t sB[2][128 * 32];

    const int tid  = threadIdx.x;
    const int wave = tid >> 6, lane = tid & 63;
    const int n0 = blockIdx.x * 128;
    const int m0 = blockIdx.y * 128;

    const int sr = wave * 16 + (lane >> 2);
    const int sc = (lane & 3) * 8;
    const half_t* gA = A + (size_t)(m0 + sr) * K + sc;
    const half_t* gB = B + (size_t)(n0 + sr) * K + sc;
    const int ldst = wave * 512;

    const int quad = lane >> 4, l16 = lane & 15;
    const int wm = (wave >> 1) * 64, wn = (wave & 1) * 64;

    f32x4 acc[4][4] = {};

    async16(gA,                  &sA[0][ldst]);
    async16(gA + (size_t)64 * K, &sA[0][2048 + ldst]);
    async16(gB,                  &sB[0][ldst]);
    async16(gB + (size_t)64 * K, &sB[0][2048 + ldst]);

    for (int ks = 0; ks < KSTEPS; ++ks) {
        __syncthreads();
        if (ks + 1 < KSTEPS) {
            const int k0 = (ks + 1) * 32;
            const int nb = (ks + 1) & 1;
            async16(gA + k0,                  &sA[nb][ldst]);
            async16(gA + (size_t)64 * K + k0, &sA[nb][2048 + ldst]);
            async16(gB + k0,                  &sB[nb][ldst]);
            async16(gB + (size_t)64 * K + k0, &sB[nb][2048 + ldst]);
        }
        const int cb = ks & 1;
        h8 af[4], bf[4];
        #pragma unroll
        for (int mi = 0; mi < 4; ++mi)
            af[mi] = *(const h8*)(&sA[cb][(wm + mi * 16 + l16) * 32 + quad * 8]);
        #pragma unroll
        for (int ni = 0; ni < 4; ++ni)
            bf[ni] = *(const h8*)(&sB[cb][(wn + ni * 16 + l16) * 32 + quad * 8]);
        #pragma unroll
        for (int mi = 0; mi < 4; ++mi)
        #pragma unroll
        for (int ni = 0; ni < 4; ++ni)
            acc[mi][ni] = __builtin_amdgcn_mfma_f32_16x16x32_f16(af[mi], bf[ni], acc[mi][ni], 0, 0, 0);
    }

    #pragma unroll
    for (int ni = 0; ni < 4; ++ni) {
        int col = n0 + wn + ni * 16 + l16;
        float bvv = bias[col];
        float s = 0.0f, ss = 0.0f;
        #pragma unroll
        for (int mi = 0; mi < 4; ++mi) {
            #pragma unroll
            for (int r = 0; r < 4; ++r) {
                int row = m0 + wm + mi * 16 + quad * 4 + r;
                float v = acc[mi][ni][r] + bvv;
                if (MODE == 0) {
                    int b   = row / NCITY;
                    int tok = row - b * NCITY;
                    int which = col >> 7;
                    int h     = (col >> 4) & 7;
                    int bh    = b * 8 + h;
                    half_t hv = (half_t)v;
                    half_t* dst = (which == 0) ? (half_t*)out
                                : (which == 1) ? (half_t*)outK : (half_t*)outV;
                    dst[((size_t)bh * NCITY + tok) * 16 + l16] = hv;
                } else {
                    size_t off = (size_t)row * Nout + col;
                    float o = v + (float)res[off];
                    ((half_t*)out)[off] = (half_t)o;
                    s += o; ss += o * o;
                }
            }
        }
        if (MODE == 1) {
            s  += __shfl_xor(s, 16);  s  += __shfl_xor(s, 32);
            ss += __shfl_xor(ss, 16); ss += __shfl_xor(ss, 32);
            if (quad == 0) {
                atomicAdd(&stats[col], s);
                atomicAdd(&stats[128 + col], ss);
            }
        }
    }
}

// ---------------- fused BN1 + FF1(ReLU) + FF2: 80 KB LDS -> 2 blocks/CU ----------------
// Input y16 (pre-BN1). x' = BN1(y16) computed inline (stats st1).
// 8 chunks of 64 hidden cols: stage wf1/wf2 chunk -> FF1 (wave tile 64x32)
// -> ReLU -> sH -> FF2 accumulate (wave tile 64x64). In-place y16 update.
__global__ __launch_bounds__(256)
void ff_fused(half_t* __restrict__ y16, const float* __restrict__ st1,
              const float* __restrict__ g1, const float* __restrict__ be1,
              const half_t* __restrict__ w1, const half_t* __restrict__ w2,
              const float* __restrict__ bf1, const float* __restrict__ bf2,
              float* __restrict__ stats)
{
    __shared__ alignas(16) half_t sX[4][128 * 32];   // 32 KB  x' tile
    __shared__ alignas(16) half_t sW1[4][64 * 32];   // 16 KB  wf1 chunk [kc][n64][32]
    __shared__ alignas(16) half_t sW2[2][128 * 32];  // 16 KB  wf2 chunk [kc][n128][32]
    __shared__ alignas(16) half_t sH[2][128 * 32];   // 16 KB  h1 chunk

    const int tid  = threadIdx.x;
    const int wave = tid >> 6, lane = tid & 63;
    const int m0 = blockIdx.x * 128;

    const int quad = lane >> 4, l16 = lane & 15;
    const int wm  = (wave >> 1) * 64;
    const int wn1 = (wave & 1) * 32;   // FF1 n within 64-chunk
    const int wn  = (wave & 1) * 64;   // FF2 n within 128

    const float invN = 1.0f / (float)TROWS;

    // stage x' = BN1(y16) into sX (register path, scale/shift on demand)
    #pragma unroll
    for (int i = 0; i < 8; ++i) {
        int u = tid + 256 * i;          // 0..2047
        int row = u >> 4;
        int c0 = (u & 15) * 8;
        h8 v = *(const h8*)(y16 + (size_t)(m0 + row) * 128 + c0);
        h8 xv;
        #pragma unroll
        for (int r = 0; r < 8; ++r) {
            int c = c0 + r;
            float mean = st1[c] * invN;
            float var  = st1[128 + c] * invN - mean * mean;
            float scl  = g1[c] * rsqrtf(var + 1e-5f);
            xv[r] = (half_t)(((float)v[r] - mean) * scl + be1[c]);
        }
        *(h8*)(&sX[c0 >> 5][row * 32 + (c0 & 31)]) = xv;
    }

    const int sr = wave * 16 + (lane >> 2);   // 0..63
    const int sc = (lane & 3) * 8;
    const int ldst = wave * 512;

    f32x4 acc2[4][4] = {};

    for (int j = 0; j < 8; ++j) {
        __syncthreads();   // j=0: sX visible; j>0: FF2(j-1) done with sW/sH
        #pragma unroll
        for (int kc = 0; kc < 4; ++kc)
            async16(w1 + (size_t)(j * 64 + sr) * 128 + kc * 32 + sc, &sW1[kc][ldst]);
        #pragma unroll
        for (int kc = 0; kc < 2; ++kc) {
            async16(w2 + (size_t)sr * 512 + j * 64 + kc * 32 + sc,        &sW2[kc][ldst]);
            async16(w2 + (size_t)(64 + sr) * 512 + j * 64 + kc * 32 + sc, &sW2[kc][2048 + ldst]);
        }
        __syncthreads();   // drain staging

        // FF1: 128m x 64n chunk, wave tile 64x32
        f32x4 acc1[4][2] = {};
        #pragma unroll
        for (int kc = 0; kc < 4; ++kc) {
            h8 af[4], bf[2];
            #pragma unroll
            for (int mi = 0; mi < 4; ++mi)
                af[mi] = *(const h8*)(&sX[kc][(wm + mi * 16 + l16) * 32 + quad * 8]);
            #pragma unroll
            for (int ni = 0; ni < 2; ++ni)
                bf[ni] = *(const h8*)(&sW1[kc][(wn1 + ni * 16 + l16) * 32 + quad * 8]);
            #pragma unroll
            for (int mi = 0; mi < 4; ++mi)
            #pragma unroll
            for (int ni = 0; ni < 2; ++ni)
                acc1[mi][ni] = __builtin_amdgcn_mfma_f32_16x16x32_f16(af[mi], bf[ni], acc1[mi][ni], 0, 0, 0);
        }
        // bias + ReLU -> sH [kc2][row][32]
        #pragma unroll
        for (int ni = 0; ni < 2; ++ni) {
            int c = wn1 + ni * 16 + l16;      // 0..63
            float bvv = bf1[j * 64 + c];
            #pragma unroll
            for (int mi = 0; mi < 4; ++mi)
            #pragma unroll
            for (int r = 0; r < 4; ++r) {
                int row = wm + mi * 16 + quad * 4 + r;
                float v = acc1[mi][ni][r] + bvv;
                v = v > 0.0f ? v : 0.0f;
                sH[c >> 5][row * 32 + (c & 31)] = (half_t)v;
            }
        }
        __syncthreads();   // sH visible

        // FF2 partial: K-slice 64, wave tile 64x64
        #pragma unroll
        for (int kc = 0; kc < 2; ++kc) {
            h8 af[4], bf[4];
            #pragma unroll
            for (int mi = 0; mi < 4; ++mi)
                af[mi] = *(const h8*)(&sH[kc][(wm + mi * 16 + l16) * 32 + quad * 8]);
            #pragma unroll
            for (int ni = 0; ni < 4; ++ni)
                bf[ni] = *(const h8*)(&sW2[kc][(wn + ni * 16 + l16) * 32 + quad * 8]);
            #pragma unroll
            for (int mi = 0; mi < 4; ++mi)
            #pragma unroll
            for (int ni = 0; ni < 4; ++ni)
                acc2[mi][ni] = __builtin_amdgcn_mfma_f32_16x16x32_f16(af[mi], bf[ni], acc2[mi][ni], 0, 0, 0);
        }
    }

    // epilogue: y2 = acc2 + bf2 + x' (x' recomputed fp32 from y16), BN2 stats
    #pragma unroll
    for (int ni = 0; ni < 4; ++ni) {
        int col = wn + ni * 16 + l16;
        float bvv = bf2[col];
        float mean = st1[col] * invN;
        float var  = st1[128 + col] * invN - mean * mean;
        float scl  = g1[col] * rsqrtf(var + 1e-5f);
        float shf  = be1[col] - mean * scl;
        float s = 0.0f, ss = 0.0f;
        #pragma unroll
        for (int mi = 0; mi < 4; ++mi) {
            #pragma unroll
            for (int r = 0; r < 4; ++r) {
                int row = m0 + wm + mi * 16 + quad * 4 + r;
                size_t off = (size_t)row * 128 + col;
                float xv = (float)y16[off] * scl + shf;
                float o = acc2[mi][ni][r] + bvv + xv;
                y16[off] = (half_t)o;
                s += o; ss += o * o;
            }
        }
        s  += __shfl_xor(s, 16);  s  += __shfl_xor(s, 32);
        ss += __shfl_xor(ss, 16); ss += __shfl_xor(ss, 32);
        if (quad == 0) {
            atomicAdd(&stats[col], s);
            atomicAdd(&stats[128 + col], ss);
        }
    }
}

// ---------------- LDS-free fp16 MFMA attention: one wave per (bh, q-tile) ----------------
__global__ __launch_bounds__(256)
void attn_kernel(const half_t* __restrict__ Qh, const half_t* __restrict__ Kh,
                 const half_t* __restrict__ V, half_t* __restrict__ oh)
{
    const int wid = blockIdx.x * 4 + (threadIdx.x >> 6);
    const int bh = wid / 7;
    const int it = wid - bh * 7;
    if (bh >= NBH) return;
    const int b = bh >> 3, h = bh & 7;

    const int lane = threadIdx.x & 63, quad = lane >> 4, l16 = lane & 15;
    const int s0 = (((quad & 1) * 2)    ) * 16 + l16;
    const int s1 = (((quad & 1) * 2) + 1) * 16 + l16;
    const bool hi2 = (quad >> 1) != 0;

    const half_t* qbase = Qh + (size_t)bh * NCITY * 16;
    const half_t* kbase = Kh + (size_t)bh * NCITY * 16;
    const half_t* vbase = V  + (size_t)bh * NCITY * 16;

    h8 qf = {};
    if (quad < 2)
        qf = *reinterpret_cast<const h8*>(qbase + (it * 16 + l16) * 16 + quad * 8);

    f32x4 S[7];
    #pragma unroll
    for (int jt = 0; jt < 7; ++jt) {
        h8 kf = {};
        if (quad < 2)
            kf = *reinterpret_cast<const h8*>(kbase + (jt * 16 + l16) * 16 + quad * 8);
        f32x4 a = {};
        a = __builtin_amdgcn_mfma_f32_16x16x32_f16(kf, qf, a, 0, 0, 0);
        S[jt] = a;
    }
    float m = -1e30f;
    #pragma unroll
    for (int jt = 0; jt < 7; ++jt)
        #pragma unroll
        for (int r = 0; r < 4; ++r) {
            int jg = jt * 16 + quad * 4 + r;
            float sv = (jg < NCITY) ? S[jt][r] * 0.25f : -1e30f;
            S[jt][r] = sv;
            m = fmaxf(m, sv);
        }
    m = fmaxf(m, __shfl_xor(m, 16));
    m = fmaxf(m, __shfl_xor(m, 32));
    float sum = 0.0f;
    #pragma unroll
    for (int jt = 0; jt < 7; ++jt)
        #pragma unroll
        for (int r = 0; r < 4; ++r) {
            float e = __expf(S[jt][r] - m);
            S[jt][r] = e;
            sum += e;
        }
    sum += __shfl_xor(sum, 16);
    sum += __shfl_xor(sum, 32);
    float inv = 1.0f / sum;
    #pragma unroll
    for (int jt = 0; jt < 7; ++jt)
        #pragma unroll
        for (int r = 0; r < 4; ++r) S[jt][r] *= inv;

    f32x4 O = {};
    #pragma unroll
    for (int p = 0; p < 4; ++p) {
        h8 vf;
        #pragma unroll
        for (int jj = 0; jj < 8; ++jj)
            vf[jj] = vbase[(size_t)(p * 32 + quad * 8 + jj) * 16 + l16];
        float pj[8];
        #pragma unroll
        for (int r = 0; r < 4; ++r) {
            float a0 = __shfl(S[2 * p][r],     s0);
            float b0 = __shfl(S[2 * p + 1][r], s0);
            float a1 = __shfl(S[2 * p][r],     s1);
            float b1 = __shfl(S[2 * p + 1][r], s1);
            pj[r]     = hi2 ? b0 : a0;
            pj[4 + r] = hi2 ? b1 : a1;
        }
        h8 ph;
        #pragma unroll
        for (int jj = 0; jj < 8; ++jj)
            ph[jj] = (half_t)pj[jj];
        O = __builtin_amdgcn_mfma_f32_16x16x32_f16(ph, vf, O, 0, 0, 0);
    }
    #pragma unroll
    for (int r = 0; r < 4; ++r) {
        int q = it * 16 + quad * 4 + r;
        if (q < NCITY)
            oh[((size_t)b * NCITY + q) * 128 + h * 16 + l16] = (half_t)O[r];
    }
}

// ---------------- BatchNorm apply (finalize folded in) ----------------
__global__ __launch_bounds__(256)
void bn_apply(const h8* __restrict__ y, const float* __restrict__ stats,
              const float* __restrict__ g, const float* __restrict__ be,
              half_t* __restrict__ xh, float* __restrict__ dst32)
{
    __shared__ float sh[256];
    const int tid = threadIdx.x;
    if (tid < 128) {
        const float invN = 1.0f / (float)TROWS;
        float mean = stats[tid] * invN;
        float var  = stats[128 + tid] * invN - mean * mean;
        float inv  = rsqrtf(var + 1e-5f);
        float scl  = g[tid] * inv;
        sh[tid]       = scl;
        sh[128 + tid] = be[tid] - mean * scl;
    }
    __syncthreads();

    int gid = blockIdx.x * 256 + tid;   // over TROWS*16 (8 ch each)
    int c = (gid & 15) * 8;
    h8 v = y[gid];
    h8 hv;
    float o[8];
    #pragma unroll
    for (int r = 0; r < 8; ++r) {
        o[r] = (float)v[r] * sh[c + r] + sh[128 + c + r];
        hv[r] = (half_t)o[r];
    }
    *reinterpret_cast<h8*>(xh + (size_t)gid * 8) = hv;
    if (dst32) {
        f32x4 lo = { o[0], o[1], o[2], o[3] };
        f32x4 hi = { o[4], o[5], o[6], o[7] };
        ((f32x4*)dst32)[gid * 2]     = lo;
        ((f32x4*)dst32)[gid * 2 + 1] = hi;
    }
}

// ---------------- launch ----------------
extern "C" void kernel_launch(void* const* d_in, const int* in_sizes, int n_in,
                              void* d_out, int out_size, void* d_ws, size_t ws_size,
                              hipStream_t stream)
{
    const float* s    = (const float*)d_in[0];
    const int*   dd   = (const int*)d_in[1];
    const float* e_w  = (const float*)d_in[2];
    const float* e_b  = (const float*)d_in[3];
    const float* ep_w = (const float*)d_in[4];
    const float* ep_b = (const float*)d_in[5];
    const float* Wq   = (const float*)d_in[6];
    const float* bq   = (const float*)d_in[7];
    const float* Wk   = (const float*)d_in[8];
    const float* bk   = (const float*)d_in[9];
    const float* Wv   = (const float*)d_in[10];
    const float* bv   = (const float*)d_in[11];
    const float* Wo   = (const float*)d_in[12];
    const float* bo   = (const float*)d_in[13];
    const float* Wf1  = (const float*)d_in[14];
    const float* bf1  = (const float*)d_in[15];
    const float* Wf2  = (const float*)d_in[16];
    const float* bf2  = (const float*)d_in[17];
    const float* g1   = (const float*)d_in[18];
    const float* be1  = (const float*)d_in[19];
    const float* g2   = (const float*)d_in[20];
    const float* be2  = (const float*)d_in[21];

    char* ws = (char*)d_ws;
    size_t off = 0;
    auto alloc = [&](size_t bytes) -> void* {
        void* p = ws + off;
        off += (bytes + 255) & ~(size_t)255;
        return p;
    };
    half_t* y16   = (half_t*)alloc((size_t)TROWS * 128 * 2);
    half_t* xh    = (half_t*)alloc((size_t)TROWS * 128 * 2);
    half_t* Qh    = (half_t*)alloc((size_t)NBH * NCITY * 16 * 2);
    half_t* Kh    = (half_t*)alloc((size_t)NBH * NCITY * 16 * 2);
    half_t* Vb    = (half_t*)alloc((size_t)NBH * NCITY * 16 * 2);
    half_t* oh    = (half_t*)alloc((size_t)TROWS * 128 * 2);
    half_t* wqkv  = (half_t*)alloc((size_t)3 * 384 * 128 * 2);
    half_t* wo    = (half_t*)alloc((size_t)3 * 128 * 128 * 2);
    half_t* wf1   = (half_t*)alloc((size_t)3 * 512 * 128 * 2);
    half_t* wf2   = (half_t*)alloc((size_t)3 * 128 * 512 * 2);
    float*  bqkv  = (float*) alloc((size_t)3 * 384 * 4);
    float*  stats = (float*) alloc(6 * 256 * 4);

    dim3 blk(256);

    hipMemsetAsync(stats, 0, 6 * 256 * 4, stream);

    prep_kernel<<<dim3(768, 7), blk, 0, stream>>>(Wq, Wk, Wv, Wo, Wf1, Wf2, bq, bk, bv,
                                                  wqkv, wo, wf1, wf2, bqkv);

    embed_kernel<<<dim3(TROWS * 128 / 256), blk, 0, stream>>>(s, dd, e_w, e_b, ep_w, ep_b, xh);

    for (int l = 0; l < 3; ++l) {
        float* st1 = stats + (size_t)(l * 2) * 256;
        float* st2 = stats + (size_t)(l * 2 + 1) * 256;
        // QKV -> Q/K/V all [bh][tok][16]
        gemm_tile<0, 4><<<dim3(3, 404), blk, 0, stream>>>(xh, wqkv + (size_t)l * 49152,
                                                          bqkv + l * 384, nullptr,
                                                          Qh, Kh, Vb, nullptr, 384);
        // attention (LDS-free fp16 MFMA)
        attn_kernel<<<dim3(7168), blk, 0, stream>>>(Qh, Kh, Vb, oh);
        // O-proj + bias + residual(xh) + fused BN1 stats -> y16
        gemm_tile<1, 4><<<dim3(1, 404), blk, 0, stream>>>(oh, wo + (size_t)l * 16384,
                                                          bo + l * 128, xh,
                                                          y16, nullptr, nullptr, st1, 128);
        // fused BN1-apply + FF1 + FF2 + residual + BN2 stats (in-place y16)
        ff_fused<<<dim3(404), blk, 0, stream>>>(y16, st1, g1 + l * 128, be1 + l * 128,
                                                wf1 + (size_t)l * 65536, wf2 + (size_t)l * 65536,
                                                bf1 + l * 512, bf2 + l * 128, st2);
        // BN2 apply -> xh (+ fp32 out on last layer)
        bn_apply<<<dim3(TROWS * 16 / 256), blk, 0, stream>>>((const h8*)y16, st2,
                                                             g2 + l * 128, be2 + l * 128,
                                                             xh, (l == 2) ? (float*)d_out : nullptr);
    }
}